// Round 1
// baseline (198.048 us; speedup 1.0000x reference)
//
#include <hip/hip_runtime.h>

// C51 categorical projection: out[row, :] = scatter of shifted/clipped atom
// masses. BS = 524288 rows, 51 atoms. Memory-bound (~219 MB HBM traffic).
//
// Layout strategy: 256 rows per block. Stage the 256x51 float tile into LDS
// with a flat coalesced copy (float4 -> ds_write_b128, no transpose, no
// division). Each thread owns one row (contiguous 51 floats in LDS at
// tid*51): read to registers, zero, scatter-add privately (no atomics),
// then flat coalesced copy back out. Row stride 51 words -> lane bank
// spread (19*tid mod 32, 19 odd) covers all 32 banks -> only free 2-way
// aliasing on the per-row accesses.

#define NUM_ATOMS 51
#define ROWS_PER_BLOCK 256
#define TILE_ELEMS (ROWS_PER_BLOCK * NUM_ATOMS)   // 13056 floats
#define TILE_VEC4 (TILE_ELEMS / 4)                // 3264 float4s -> 12288 elems
#define VEC4_ITERS 12                             // 12 * 256 = 3072... see below
// 12 iterations of 256 float4s = 3072 float4s = 12288 elements; remainder 768
#define REM_ITERS 3                               // 3 * 256 = 768

__global__ __launch_bounds__(256, 3) void catproj_kernel(
    const float* __restrict__ reward,
    const float* __restrict__ probs,
    const float* __restrict__ not_done,
    float* __restrict__ out)
{
    __shared__ float lds[TILE_ELEMS];             // 52224 B -> 3 blocks/CU

    const int tid = threadIdx.x;
    const int row = blockIdx.x * ROWS_PER_BLOCK + tid;
    const int base = blockIdx.x * TILE_ELEMS;     // max ~26.7M, fits int32

    // Per-row scalars (coalesced dword loads)
    const float r  = reward[row];
    const float nd = not_done[row];

    // ---- Stage probs tile into LDS: flat coalesced copy ----
    const float4* __restrict__ p4 = (const float4*)(probs + base);
    float4* __restrict__ l4 = (float4*)lds;
#pragma unroll
    for (int k = 0; k < VEC4_ITERS; ++k) {
        const int i4 = k * ROWS_PER_BLOCK + tid;  // [0, 3072)
        l4[i4] = p4[i4];
    }
#pragma unroll
    for (int k = 0; k < REM_ITERS; ++k) {
        const int g = VEC4_ITERS * ROWS_PER_BLOCK * 4 + k * ROWS_PER_BLOCK + tid;
        lds[g] = probs[base + g];
    }
    __syncthreads();

    // ---- Read own row into registers (static indices -> stays in VGPRs) ----
    float* __restrict__ myrow = lds + tid * NUM_ATOMS;
    float p[NUM_ATOMS];
#pragma unroll
    for (int a = 0; a < NUM_ATOMS; ++a) p[a] = myrow[a];

    // Own row region is exclusively this thread's from here: no barrier needed
#pragma unroll
    for (int a = 0; a < NUM_ATOMS; ++a) myrow[a] = 0.0f;

    // ---- Projection scatter (thread-private, in-order LDS RMW) ----
    const float c = 0.99f * nd;                   // DISCOUNT * not_done
#pragma unroll
    for (int a = 0; a < NUM_ATOMS; ++a) {
        const float z   = -10.0f + 0.4f * (float)a;       // atom value
        float nav = r + c * z;
        nav = fminf(fmaxf(nav, -10.0f), 10.0f);           // clip to support
        const float b  = (nav + 10.0f) * 2.5f;            // in [0, 50]
        const float lf = floorf(b);
        const float uf = ceilf(b);
        const int   li = (int)lf;
        const int   ui = (int)uf;
        const float wl = (uf - b) + ((li == ui) ? 1.0f : 0.0f);
        const float wu = b - lf;
        myrow[li] += wl * p[a];
        myrow[ui] += wu * p[a];
    }
    __syncthreads();

    // ---- Flat coalesced writeout ----
    float4* __restrict__ o4 = (float4*)(out + base);
#pragma unroll
    for (int k = 0; k < VEC4_ITERS; ++k) {
        const int i4 = k * ROWS_PER_BLOCK + tid;
        o4[i4] = l4[i4];
    }
#pragma unroll
    for (int k = 0; k < REM_ITERS; ++k) {
        const int g = VEC4_ITERS * ROWS_PER_BLOCK * 4 + k * ROWS_PER_BLOCK + tid;
        out[base + g] = lds[g];
    }
}

extern "C" void kernel_launch(void* const* d_in, const int* in_sizes, int n_in,
                              void* d_out, int out_size, void* d_ws, size_t ws_size,
                              hipStream_t stream) {
    const float* reward   = (const float*)d_in[0];
    const float* probs    = (const float*)d_in[1];
    const float* not_done = (const float*)d_in[2];
    float* out = (float*)d_out;

    const int bs = in_sizes[0];                   // 524288
    const int grid = bs / ROWS_PER_BLOCK;         // 2048 blocks (bs % 256 == 0)
    catproj_kernel<<<grid, ROWS_PER_BLOCK, 0, stream>>>(reward, probs, not_done, out);
}